// Round 8
// baseline (59.186 us; speedup 1.0000x reference)
//
#include <hip/hip_runtime.h>

// Problem constants (from reference): B=16, L=4096, D=1024, K=64
#define Bn 16
#define Ln 4096
#define Dn 1024
#define Kn 64
#define PT 64                  // compacted positions per stage1 block (segment)
#define CJ 16                  // compacted positions per slot chunk
#define CPS (PT / CJ)          // 4 chunks per segment
#define NSEG (Ln / PT)         // 64 segments per batch (worst case M = Ln)
#define SLOTS (CPS + 1)        // 5 slots: excl prefix at chunk j, slot 4 = seg total
#define NSPAN (2 * Bn * Kn)    // 2048 span ints

static __device__ __forceinline__ void acc4(float4& a, const float4 v) {
    a.x += v.x; a.y += v.y; a.z += v.z; a.w += v.w;
}
static __device__ __forceinline__ void sub4(float4& a, const float4 v) {
    a.x -= v.x; a.y -= v.y; a.z -= v.z; a.w -= v.w;
}
static __device__ __forceinline__ void acc4w(float4& a, const float4 v, float w) {
    a.x += v.x * w; a.y += v.y * w; a.z += v.z * w; a.w += v.w * w;
}

// ---------------------------------------------------------------------------
// Stage0: grid = Bn + 1 blocks.
//  - blocks 0..Bn-1: per-batch scan of attention_mask producing
//      Pam[b][l]  = sum of am[b][0..l)          (value prefix, for mask_sum)
//      Pcnt[b][l] = count of am[b][0..l) != 0   (count prefix, for compaction)
//      idxw[b][q] = (token index, weight) of q-th attended token
//  - block Bn: canonicalize sent_spans to int32 (int64 layout detect).
// ---------------------------------------------------------------------------
__global__ __launch_bounds__(256) void stage0_kernel(
    const int* __restrict__ am, const unsigned int* __restrict__ spans_raw,
    int* __restrict__ Pam, int* __restrict__ Pcnt, int2* __restrict__ idxw,
    int* __restrict__ dec) {
    const int bc = blockIdx.x;

    if (bc < Bn) {
        const int b = bc;
        const int t = threadIdx.x;
        const int i0 = t * 16;
        const int* amb = am + (size_t)b * Ln;
        int a[16];
        int vsum = 0, csum = 0;
#pragma unroll
        for (int j = 0; j < 16; ++j) {
            a[j] = amb[i0 + j];
            vsum += a[j];
            csum += (a[j] != 0) ? 1 : 0;
        }
        __shared__ int sv[256], sc[256];
        sv[t] = vsum; sc[t] = csum;
        __syncthreads();
        for (int off = 1; off < 256; off <<= 1) {
            int pv = (t >= off) ? sv[t - off] : 0;
            int pc = (t >= off) ? sc[t - off] : 0;
            __syncthreads();
            sv[t] += pv; sc[t] += pc;
            __syncthreads();
        }
        int vo = sv[t] - vsum;              // exclusive prefixes at token i0
        int co = sc[t] - csum;
        int* pamb = Pam + (size_t)b * (Ln + 1);
        int* pcb  = Pcnt + (size_t)b * (Ln + 1);
        int2* iwb = idxw + (size_t)b * Ln;
#pragma unroll
        for (int j = 0; j < 16; ++j) {
            pamb[i0 + j] = vo;
            pcb[i0 + j]  = co;
            if (a[j] != 0) { iwb[co] = make_int2(i0 + j, a[j]); ++co; }
            vo += a[j];
        }
        if (t == 255) { pamb[Ln] = vo; pcb[Ln] = co; }
    } else {
        // ---- span decode ----
        __shared__ unsigned int sred[256];
        unsigned int acc = 0;
        for (int i = threadIdx.x; i < NSPAN / 2; i += 256)
            acc |= spans_raw[2 * i + 1];
        sred[threadIdx.x] = acc;
        __syncthreads();
        for (int off = 128; off > 0; off >>= 1) {
            if ((int)threadIdx.x < off) sred[threadIdx.x] |= sred[threadIdx.x + off];
            __syncthreads();
        }
        const bool is64 = (sred[0] == 0u);
        for (int i = threadIdx.x; i < NSPAN; i += 256)
            dec[i] = is64 ? (int)spans_raw[2 * i] : (int)spans_raw[i];
    }
}

// ---------------------------------------------------------------------------
// Stage1: stream COMPACTED attended rows, branch-free hot loop.
// grid = Bn*NSEG blocks; block (b,r) handles compacted positions
// [r*PT, r*PT+PT) of batch b. Writes segment-local exclusive prefix slots
// every CJ positions + segment total. Loads batched 8-deep (unconditional)
// so HBM latency pipelines; blocks fully beyond M exit immediately.
// ---------------------------------------------------------------------------
__global__ __launch_bounds__(256) void stage1_kernel(
    const float* __restrict__ x, const int* __restrict__ Pcnt,
    const int2* __restrict__ idxw, float* __restrict__ G) {
    const int blk = blockIdx.x;
    const int b = blk / NSEG;
    const int r = blk % NSEG;
    const int p0 = r * PT;
    const int M = Pcnt[(size_t)b * (Ln + 1) + Ln];
    if (p0 >= M) return;                   // fully idle segment (never read)

    const int d0 = threadIdx.x * 4;
    float* g = G + (size_t)blk * SLOTS * Dn + d0;
    const float* xb = x + (size_t)b * Ln * Dn + d0;
    const int2* iwb = idxw + (size_t)b * Ln + p0;

    float4 acc = {0.f, 0.f, 0.f, 0.f};
    if (p0 + PT <= M) {
        // full path: zero branches, 8-deep load batches
#pragma unroll
        for (int j = 0; j < CPS; ++j) {
            *(float4*)(g + (size_t)j * Dn) = acc;   // exclusive prefix slot j
#pragma unroll
            for (int h = 0; h < 2; ++h) {
                int2 iw[8];
#pragma unroll
                for (int t = 0; t < 8; ++t) iw[t] = iwb[j * CJ + h * 8 + t];
                float4 v[8];
#pragma unroll
                for (int t = 0; t < 8; ++t)
                    v[t] = *(const float4*)(xb + (size_t)iw[t].x * Dn);
                float4 s0 = {0.f,0.f,0.f,0.f}, s1 = {0.f,0.f,0.f,0.f};
#pragma unroll
                for (int t = 0; t < 8; t += 2) {
                    acc4w(s0, v[t],     (float)iw[t].y);
                    acc4w(s1, v[t + 1], (float)iw[t + 1].y);
                }
                acc4(s0, s1);
                acc4(acc, s0);
            }
        }
        *(float4*)(g + (size_t)CPS * Dn) = acc;     // segment total
    } else {
        // partial tail segment (at most one per batch)
        for (int j = 0; j < CPS; ++j) {
            *(float4*)(g + (size_t)j * Dn) = acc;
            for (int t = 0; t < CJ; ++t) {
                const int p = p0 + j * CJ + t;
                if (p < M) {
                    const int2 iw = iwb[j * CJ + t];
                    const float4 v = *(const float4*)(xb + (size_t)iw.x * Dn);
                    acc4w(acc, v, (float)iw.y);
                }
            }
        }
        *(float4*)(g + (size_t)CPS * Dn) = acc;
    }
}

// ---------------------------------------------------------------------------
// K2: per-span pooling in compacted space. grid = B*K blocks, 256 threads.
// msum = Pam[e]-Pam[s]; compacted range [pa,pb) = [Pcnt[s],Pcnt[e]).
// Interior = slot diffs (+ middle segment totals); edges = <=15 gathered
// rows per side via idxw. !use_am (rare): plain mean over [s,e) from x.
// ---------------------------------------------------------------------------
__global__ __launch_bounds__(256) void span_pool_kernel(
    const float* __restrict__ x, const int* __restrict__ spans,
    const float* __restrict__ G, const int* __restrict__ Pam,
    const int* __restrict__ Pcnt, const int2* __restrict__ idxw,
    float* __restrict__ H, float* __restrict__ sent_mask) {
    const int bk = blockIdx.x;          // b*K + k
    const int b = bk / Kn;

    int s = spans[2 * bk];
    int e = spans[2 * bk + 1];
    if (s < 0) s = 0; if (s > Ln) s = Ln;
    if (e < 0) e = 0; if (e > Ln) e = Ln;
    const int len = (e > s) ? (e - s) : 0;
    if (e < s) e = s;

    const int* pamb = Pam + (size_t)b * (Ln + 1);
    const int* pcb  = Pcnt + (size_t)b * (Ln + 1);
    const int msum = pamb[e] - pamb[s];
    const bool use_am = (msum > 0);
    const bool valid = (len > 0);

    const int d0 = threadIdx.x * 4;
    const float* xb = x + (size_t)b * Ln * Dn + d0;
    float4 acc = {0.f, 0.f, 0.f, 0.f};

    if (!use_am) {
        // rare: no attended tokens in span -> plain mean over [s,e)
        for (int l = s; l < e; ++l)
            acc4(acc, *(const float4*)(xb + (size_t)l * Dn));
    } else {
        const int pa = pcb[s];
        const int pb = pcb[e];
        const int2* iwb = idxw + (size_t)b * Ln;
        const int bnd_a = ((pa + CJ - 1) / CJ) * CJ;   // first boundary >= pa
        const int bnd_b = (pb / CJ) * CJ;              // last boundary <= pb

        if (bnd_a <= bnd_b) {
            const int ca = bnd_a / CJ;     // global chunk indices
            const int cbk = bnd_b / CJ;
            if (cbk > ca) {
                const float* Gb = G + (size_t)b * NSEG * SLOTS * Dn + d0;
                const int sa = ca / CPS, ja = ca % CPS;
                const int sb = cbk / CPS, jb = cbk % CPS;
                if (sa == sb) {
                    acc = *(const float4*)(Gb + (size_t)(sa * SLOTS + jb) * Dn);
                    sub4(acc, *(const float4*)(Gb + (size_t)(sa * SLOTS + ja) * Dn));
                } else {
                    acc = *(const float4*)(Gb + (size_t)(sa * SLOTS + CPS) * Dn);
                    sub4(acc, *(const float4*)(Gb + (size_t)(sa * SLOTS + ja) * Dn));
                    float4 m0 = {0.f,0.f,0.f,0.f}, m1 = {0.f,0.f,0.f,0.f};
                    int ss = sa + 1;
                    for (; ss + 1 < sb; ss += 2) {
                        acc4(m0, *(const float4*)(Gb + (size_t)(ss * SLOTS + CPS) * Dn));
                        acc4(m1, *(const float4*)(Gb + (size_t)((ss + 1) * SLOTS + CPS) * Dn));
                    }
                    if (ss < sb)
                        acc4(m0, *(const float4*)(Gb + (size_t)(ss * SLOTS + CPS) * Dn));
                    acc4(acc, m0); acc4(acc, m1);
                    if (jb > 0)
                        acc4(acc, *(const float4*)(Gb + (size_t)(sb * SLOTS + jb) * Dn));
                }
            }
            // edge gathers [pa, bnd_a) and [bnd_b, pb)
            for (int p = pa; p < bnd_a; ++p) {
                const int2 iw = iwb[p];
                acc4w(acc, *(const float4*)(xb + (size_t)iw.x * Dn), (float)iw.y);
            }
            for (int p = bnd_b; p < pb; ++p) {
                const int2 iw = iwb[p];
                acc4w(acc, *(const float4*)(xb + (size_t)iw.x * Dn), (float)iw.y);
            }
        } else {
            // no slot boundary inside range: gather everything (< CJ*2 rows)
            for (int p = pa; p < pb; ++p) {
                const int2 iw = iwb[p];
                acc4w(acc, *(const float4*)(xb + (size_t)iw.x * Dn), (float)iw.y);
            }
        }
    }

    const float denom = use_am ? (float)msum : (float)len;
    const float inv = valid ? (1.0f / denom) : 0.0f;
    float4 outv;
    outv.x = acc.x * inv; outv.y = acc.y * inv;
    outv.z = acc.z * inv; outv.w = acc.w * inv;

    *(float4*)(H + (size_t)bk * Dn + d0) = outv;
    if (threadIdx.x == 0) sent_mask[bk] = valid ? 1.0f : 0.0f;
}

extern "C" void kernel_launch(void* const* d_in, const int* in_sizes, int n_in,
                              void* d_out, int out_size, void* d_ws, size_t ws_size,
                              hipStream_t stream) {
    const float* x = (const float*)d_in[0];
    const int* am = (const int*)d_in[1];
    const unsigned int* spans_raw = (const unsigned int*)d_in[2];

    float* H = (float*)d_out;
    float* sent_mask = H + (size_t)Bn * Kn * Dn;

    // workspace layout: dec | Pam | Pcnt | idxw | G
    const size_t dec_bytes  = 8192;                                  // >= NSPAN*4
    const size_t pref_bytes = (size_t)Bn * (Ln + 1) * sizeof(int);   // 262208 B
    const size_t idxw_bytes = (size_t)Bn * Ln * sizeof(int2);        // 524288 B
    char* w = (char*)d_ws;
    int*  dec  = (int*)w;                         w += dec_bytes;
    int*  Pam  = (int*)w;                         w += pref_bytes;
    int*  Pcnt = (int*)w;                         w += pref_bytes + (16 - (pref_bytes % 16)) % 16;
    int2* idxw = (int2*)w;                        w += idxw_bytes;
    float* G   = (float*)w;                       // 16*64*5*4KB ~= 21 MB

    stage0_kernel<<<Bn + 1, 256, 0, stream>>>(am, spans_raw, Pam, Pcnt, idxw, dec);
    stage1_kernel<<<Bn * NSEG, 256, 0, stream>>>(x, Pcnt, idxw, G);
    span_pool_kernel<<<Bn * Kn, 256, 0, stream>>>(
        x, dec, G, Pam, Pcnt, idxw, H, sent_mask);
}